// Round 18
// baseline (1492.614 us; speedup 1.0000x reference)
//
#include <hip/hip_runtime.h>
#include <hip/hip_bf16.h>

// ---------------------------------------------------------------------------
// LSTM_37847251812594: 2-layer LSTM (B=256, T=64, n_x=512, n_h=1024) + FC+softmax
// Round 18: 32x32x16 MFMA — halve LDS A-traffic with zero added sync.
//   - block owns 8 hidden = 32 gate-rows = ONE 32x32 A-tile; 8 waves x 32
//     batch-cols (512 thr). Per CU: LDS A-reads 2MB -> 1MB, B unchanged.
//   - C/D layout (m101): lane (hi,col) holds rows j+8g+4hi for ALL g ->
//     all 4 gates x 4 hidden of a cell in-register: SHFL-FREE epilogue,
//     one 8-B h store + optional 16-B h1f store per lane.
//   - h/x frag-major v2 for 32-col fragments: [mg8][kc16][lane][8];
//     writer (cvt/epilogue) and reader co-designed.
//   - r17's decoupled per-layer barriers + 4-slot h0 ring kept (helped).
//   - k-rotation on 16-wide chunks; unroll-8 I$-safe loops.
// ---------------------------------------------------------------------------

typedef short  bf16x8 __attribute__((ext_vector_type(8)));
typedef float  f32x4  __attribute__((ext_vector_type(4)));
typedef float  f32x16 __attribute__((ext_vector_type(16)));

#define NHID   1024
#define NBATCH 256
#define NBLK   256
#define HSZE   (NBATCH * NHID)

__device__ __forceinline__ unsigned short f2b(float f) {
    unsigned int u = __builtin_bit_cast(unsigned int, f);
    unsigned int r = (u + 0x7FFFu + ((u >> 16) & 1u)) >> 16;
    return (unsigned short)r;
}
__device__ __forceinline__ float sigmoidf_(float x) {
    return 1.0f / (1.0f + __expf(-x));
}
__device__ __forceinline__ float tanhf_(float x) {
    return 1.0f - 2.0f / (__expf(2.0f * x) + 1.0f);
}

// Transpose+convert: W[k][n] fp32 -> Wt[g][n][k] bf16, LDS-tiled 64x64.
__global__ __launch_bounds__(256)
void transpose_w_kernel(const float* __restrict__ w0, const float* __restrict__ w1,
                        const float* __restrict__ w2, const float* __restrict__ w3,
                        unsigned short* __restrict__ dst, int nv) {
    __shared__ unsigned short t[64][65];
    const int gate = blockIdx.z;
    const float* src = (gate == 0) ? w0 : (gate == 1) ? w1 : (gate == 2) ? w2 : w3;
    const int kt = blockIdx.x * 64;
    const int nt = blockIdx.y * 64;
    const int tid = threadIdx.x;
    const int rr = tid >> 6;
    const int cc = tid & 63;
    #pragma unroll
    for (int p = 0; p < 16; ++p) {
        const int row = p * 4 + rr;
        t[cc][row] = f2b(src[(size_t)(kt + row) * NHID + nt + cc]);
    }
    __syncthreads();
    #pragma unroll
    for (int p = 0; p < 16; ++p) {
        const int row = p * 4 + rr;
        dst[((size_t)gate * NHID + nt + row) * nv + kt + cc] = t[row][cc];
    }
}

// x -> bf16, frag-major v2 per timestep for 32x32 MFMA B-operand:
// xb[t][mg 0..7][kc 0..31][lane][8], lane = kh*32+col, k = kc*16 + kh*8 + e.
__global__ __launch_bounds__(256)
void cvt_x_frag_kernel(const float* __restrict__ x, unsigned short* __restrict__ xb) {
    const int t  = blockIdx.x;        // 0..63
    const int mg = blockIdx.y;        // 0..7 (32 batch rows each)
    const int l  = threadIdx.x & 63;
    const int q  = threadIdx.x >> 6;  // 0..3
    const int col = l & 31, kh2 = l >> 5;
    const float* srcm = x + (size_t)(mg * 32 + col) * 32768 + t * 512;
    unsigned short* dstb = xb + (((size_t)t * 8 + mg) * 32 * 64 + l) * 8;
    #pragma unroll
    for (int i = 0; i < 8; ++i) {
        const int kc = q * 8 + i;
        const int k  = kc * 16 + kh2 * 8;
        const float4 v0 = *(const float4*)(srcm + k);
        const float4 v1 = *(const float4*)(srcm + k + 4);
        ushort4 o0, o1;
        o0.x = f2b(v0.x); o0.y = f2b(v0.y); o0.z = f2b(v0.z); o0.w = f2b(v0.w);
        o1.x = f2b(v1.x); o1.y = f2b(v1.y); o1.z = f2b(v1.z); o1.w = f2b(v1.w);
        unsigned short* d = dstb + (size_t)kc * 512;
        *(ushort4*)(d)     = o0;
        *(ushort4*)(d + 4) = o1;
    }
}

// Per-layer group barrier (128 blocks: 4 groups x 32) + cross-layer epoch
// gating (r17): L1 waits gctr_L0 >= gen+1; L0 (gen>=2) waits gctr_L1 >= gen-1.
__device__ __forceinline__ void layer_sync(unsigned* bar, unsigned gen,
                                           int layer, int lb) {
    __syncthreads();
    if (threadIdx.x == 0) {
        __builtin_amdgcn_fence(__ATOMIC_RELEASE, "agent");
        unsigned* base = bar + layer * 96;
        unsigned* grp  = base + (lb & 3) * 16;
        unsigned* stg  = base + 64;
        unsigned* gctr = base + 80;
        unsigned* octr = bar + (layer ? 80 : 176);
        if (__hip_atomic_fetch_add(grp, 1u, __ATOMIC_RELAXED, __HIP_MEMORY_SCOPE_AGENT)
                == gen * 32u + 31u) {
            if (__hip_atomic_fetch_add(stg, 1u, __ATOMIC_RELAXED, __HIP_MEMORY_SCOPE_AGENT)
                    == gen * 4u + 3u)
                __hip_atomic_store(gctr, gen + 1u, __ATOMIC_RELAXED, __HIP_MEMORY_SCOPE_AGENT);
        }
        while (__hip_atomic_load(gctr, __ATOMIC_RELAXED, __HIP_MEMORY_SCOPE_AGENT) <= gen)
            __builtin_amdgcn_s_sleep(2);
        if (layer == 1) {
            while (__hip_atomic_load(octr, __ATOMIC_RELAXED, __HIP_MEMORY_SCOPE_AGENT) <= gen)
                __builtin_amdgcn_s_sleep(2);
        } else if (gen >= 2) {
            while (__hip_atomic_load(octr, __ATOMIC_RELAXED, __HIP_MEMORY_SCOPE_AGENT) < gen - 1u)
                __builtin_amdgcn_s_sleep(2);
        }
        __builtin_amdgcn_fence(__ATOMIC_ACQUIRE, "agent");
    }
    __syncthreads();
}

// Persistent kernel, layer-split, 512 threads = 8 waves, 32x32x16 MFMA.
// layer = (b>>3)&1; lb = (b>>4)*8 + (b&7) in [0,128).
// Block owns hidden [8*lb, 8*lb+8): 32 gate-rows R = gate*8 + hl.
// Wave w owns batch cols [32w, 32w+32).
// LDS: lw[kc][lane][8] bf16; kc 0..63 = h-part (k=kc*16), kc 64.. = x-part.
// A-frag: lane row = lane&31 (=R), k = kc*16 + (lane>>5)*8 + e.
// C/D (m101): col = lane&31, row = (r&3) + 8*(r>>2) + 4*(lane>>5)
//   -> lane holds gates g=r>>2 at hl = (r&3) + 4*hi: 4 full cells in-register.
__global__ __launch_bounds__(512, 2)
void lstm_persist_kernel(const unsigned short* __restrict__ wt0,   // [4][1024][1536]
                         const unsigned short* __restrict__ wt1,   // [4][1024][2048]
                         const unsigned short* __restrict__ xb,    // frag-major v2
                         const float* __restrict__ bf0, const float* __restrict__ bi0,
                         const float* __restrict__ bc0, const float* __restrict__ bo0,
                         const float* __restrict__ bf1, const float* __restrict__ bi1,
                         const float* __restrict__ bc1, const float* __restrict__ bo1,
                         unsigned short* __restrict__ h0b,   // [4] frag-major v2 ring
                         unsigned short* __restrict__ h1b,   // [2] frag-major v2
                         float* __restrict__ h1f,            // [256][1024] fp32 plain
                         unsigned* __restrict__ bar) {
    __shared__ __align__(16) unsigned short lw[65536];   // up to 128 KB

    const int tid  = threadIdx.x;
    const int lane = tid & 63;
    const int w    = tid >> 6;     // wave 0..7 -> batch cols [32w, 32w+32)
    const int col  = lane & 31;
    const int hi   = lane >> 5;    // 0..1
    const int b    = blockIdx.x;
    const int layer = (b >> 3) & 1;
    const int lb    = ((b >> 4) << 3) | (b & 7);   // 0..127 within layer

    const unsigned short* wt = layer ? wt1 : wt0;
    const int NV  = layer ? 2048 : 1536;
    const int NCW = NV >> 4;            // 96 or 128 k16-chunks
    const int NX  = layer ? 64 : 32;    // x-part k16-chunks

    // ---- stage this block's 32 gate-rows into LDS, A-fragment order ----
    {
        const int R   = lane & 31;           // gate-row
        const int g   = R >> 3;
        const int hid = 8 * lb + (R & 7);
        const unsigned short* s = wt + ((size_t)g * NHID + hid) * NV + hi * 8;
        #pragma unroll
        for (int i = 0; i < 16; ++i) {
            const int kc = w + i * 8;
            if (kc < NCW)
                *(bf16x8*)(lw + ((size_t)kc * 64 + lane) * 8) =
                    *(const bf16x8*)(s + kc * 16);
        }
    }

    // bias vector: biasv[4g+j] = bias_g[8lb + 4hi + j]
    f32x16 biasv;
    {
        const float* bp[4];
        if (layer) { bp[0] = bf1; bp[1] = bi1; bp[2] = bc1; bp[3] = bo1; }
        else       { bp[0] = bf0; bp[1] = bi0; bp[2] = bc0; bp[3] = bo0; }
        #pragma unroll
        for (int g = 0; g < 4; ++g) {
            const float4 v = *(const float4*)(bp[g] + 8 * lb + 4 * hi);
            biasv[4 * g + 0] = v.x; biasv[4 * g + 1] = v.y;
            biasv[4 * g + 2] = v.z; biasv[4 * g + 3] = v.w;
        }
    }
    __syncthreads();

    float cs[4] = {0.f, 0.f, 0.f, 0.f};   // 4 cells: m=32w+col, hid 8lb+4hi+j
    unsigned gen = 0;

    const int rot_h  = (b >> 3) & 63;
    const int rot_xL = layer ? ((b >> 3) & 63) : ((b >> 4) & 31);

    // h-write position, frag-major v2: H = 8lb + 4hi + j -> kc = lb>>1,
    // lane_dst = (lb&1)*32 + col, e = 4hi + j (4 consecutive -> 8-B store)
    const size_t hoff = (((size_t)w * 64 + (lb >> 1)) * 64 + (lb & 1) * 32 + col) * 8 + 4 * hi;
    const int mrow = 32 * w + col;

    auto step = [&](const int NXc, const int rot_x,
                    const unsigned short* bh, const unsigned short* bx,
                    unsigned short* hout, float* hfout) {
        f32x16 acc = biasv;
        const unsigned short* ph = bh + ((size_t)w * 64 * 64 + lane) * 8;
        const unsigned short* px = bx + ((size_t)w * NXc * 64 + lane) * 8;

        #pragma unroll 8
        for (int i = 0; i < 64; ++i) {
            const int kc = (i + rot_h) & 63;
            const bf16x8 vb = *(const bf16x8*)(ph + (size_t)kc * 512);
            const bf16x8 va = *(const bf16x8*)(lw + ((size_t)kc * 64 + lane) * 8);
            acc = __builtin_amdgcn_mfma_f32_32x32x16_bf16(va, vb, acc, 0, 0, 0);
        }
        #pragma unroll 8
        for (int i = 0; i < NXc; ++i) {
            const int kc = (i + rot_x) & (NXc - 1);
            const bf16x8 vb = *(const bf16x8*)(px + (size_t)kc * 512);
            const bf16x8 va = *(const bf16x8*)(lw + ((size_t)(64 + kc) * 64 + lane) * 8);
            acc = __builtin_amdgcn_mfma_f32_32x32x16_bf16(va, vb, acc, 0, 0, 0);
        }

        // shfl-free epilogue: gates F=acc[j], I=acc[4+j], C=acc[8+j], O=acc[12+j]
        float hv[4];
        #pragma unroll
        for (int j = 0; j < 4; ++j) {
            const float fv = sigmoidf_(acc[j]);
            const float iv = sigmoidf_(acc[4 + j]);
            const float cv = tanhf_(acc[8 + j]);
            const float ov = sigmoidf_(acc[12 + j]);
            const float cc = fv * cs[j] + iv * cv;
            const float hh = ov * tanhf_(cc);
            cs[j] = cc;
            hv[j] = hh;
        }
        ushort4 hb;
        hb.x = f2b(hv[0]); hb.y = f2b(hv[1]); hb.z = f2b(hv[2]); hb.w = f2b(hv[3]);
        *reinterpret_cast<ushort4*>(hout + hoff) = hb;
        if (hfout) {
            float4 hf; hf.x = hv[0]; hf.y = hv[1]; hf.z = hv[2]; hf.w = hv[3];
            *reinterpret_cast<float4*>(hfout + (size_t)mrow * NHID + 8 * lb + 4 * hi) = hf;
        }
    };

    // pipeline: iter t: L0 does L0[t] (h0 ring slot t&3), L1 does L1[t-1];
    // per-layer barriers + epoch flow control (r17).
    for (int t = 0; t <= 64; ++t) {
        if (layer == 0) {
            if (t < 64) {
                step(32, rot_xL,
                     h0b + (size_t)((t + 3) & 3) * HSZE,
                     xb + (size_t)t * 8 * 32 * 64 * 8,
                     h0b + (size_t)(t & 3) * HSZE, nullptr);
            }
        } else {
            if (t >= 1) {
                const int u = t - 1;
                step(64, rot_xL,
                     h1b + (size_t)((u + 1) & 1) * HSZE,
                     h0b + (size_t)(u & 3) * HSZE,
                     h1b + (size_t)(u & 1) * HSZE,
                     (u == 63) ? h1f : nullptr);
            }
        }
        if (t < 64) {
            layer_sync(bar, gen, layer, lb);
            ++gen;
        }
    }
}

// logits = h1 @ W + b : grid (4 n-blocks, 64 m-blocks), 4 m-rows staged in LDS.
__global__ __launch_bounds__(256)
void classifier_kernel(const float* __restrict__ h, const float* __restrict__ W,
                       const float* __restrict__ b, float* __restrict__ logits) {
    __shared__ float hs[4 * 1024];
    const int tid = threadIdx.x;
    const int m0 = blockIdx.y * 4;
    const int n  = blockIdx.x * 256 + tid;
    #pragma unroll
    for (int i = 0; i < 16; ++i)
        hs[i * 256 + tid] = h[(size_t)m0 * NHID + i * 256 + tid];
    __syncthreads();
    if (n < 1000) {
        float a0 = 0.f, a1 = 0.f, a2 = 0.f, a3 = 0.f;
        #pragma unroll 8
        for (int k = 0; k < NHID; ++k) {
            const float wv = W[(size_t)k * 1000 + n];
            a0 = fmaf(hs[k], wv, a0);
            a1 = fmaf(hs[1024 + k], wv, a1);
            a2 = fmaf(hs[2048 + k], wv, a2);
            a3 = fmaf(hs[3072 + k], wv, a3);
        }
        const float bv = b[n];
        logits[(size_t)(m0 + 0) * 1000 + n] = a0 + bv;
        logits[(size_t)(m0 + 1) * 1000 + n] = a1 + bv;
        logits[(size_t)(m0 + 2) * 1000 + n] = a2 + bv;
        logits[(size_t)(m0 + 3) * 1000 + n] = a3 + bv;
    }
}

__global__ void softmax_kernel(const float* __restrict__ logits, float* __restrict__ pred) {
    __shared__ float red[256];
    const int m = blockIdx.x;
    const int t = threadIdx.x;
    const float* lr = logits + (size_t)m * 1000;
    float mx = -3.4e38f;
    for (int i = t; i < 1000; i += 256) mx = fmaxf(mx, lr[i]);
    red[t] = mx; __syncthreads();
    for (int off = 128; off > 0; off >>= 1) {
        if (t < off) red[t] = fmaxf(red[t], red[t + off]);
        __syncthreads();
    }
    mx = red[0];
    __syncthreads();
    float sm = 0.0f;
    for (int i = t; i < 1000; i += 256) sm += __expf(lr[i] - mx);
    red[t] = sm; __syncthreads();
    for (int off = 128; off > 0; off >>= 1) {
        if (t < off) red[t] += red[t + off];
        __syncthreads();
    }
    const float inv = 1.0f / red[0];
    for (int i = t; i < 1000; i += 256)
        pred[(size_t)m * 1000 + i] = __expf(lr[i] - mx) * inv;
}

extern "C" void kernel_launch(void* const* d_in, const int* in_sizes, int n_in,
                              void* d_out, int out_size, void* d_ws, size_t ws_size,
                              hipStream_t stream) {
    (void)in_sizes; (void)n_in; (void)out_size; (void)ws_size;
    const float* x = (const float*)d_in[0];
    const float* W0[4] = {(const float*)d_in[1], (const float*)d_in[2], (const float*)d_in[3], (const float*)d_in[4]};
    const float* B0[4] = {(const float*)d_in[5], (const float*)d_in[6], (const float*)d_in[7], (const float*)d_in[8]};
    const float* W1[4] = {(const float*)d_in[9], (const float*)d_in[10], (const float*)d_in[11], (const float*)d_in[12]};
    const float* B1[4] = {(const float*)d_in[13], (const float*)d_in[14], (const float*)d_in[15], (const float*)d_in[16]};
    const float* Wc = (const float*)d_in[17];
    const float* bc = (const float*)d_in[18];
    float* out = (float*)d_out;

    char* ws = (char*)d_ws;
    size_t off = 0;
    auto alloc = [&](size_t bytes) -> char* {
        char* p = ws + off;
        off += (bytes + 255) & ~(size_t)255;
        return p;
    };
    unsigned short* wt0 = (unsigned short*)alloc((size_t)4 * NHID * 1536 * 2);
    unsigned short* wt1 = (unsigned short*)alloc((size_t)4 * NHID * 2048 * 2);
    unsigned short* xb  = (unsigned short*)alloc((size_t)NBATCH * 64 * 512 * 2);
    char* hstates = ws + off;
    unsigned short* h0b = (unsigned short*)alloc((size_t)4 * HSZE * 2);   // 4-slot ring
    unsigned short* h1b = (unsigned short*)alloc((size_t)2 * HSZE * 2);
    size_t hstate_bytes = (size_t)((char*)h1b + (size_t)2 * HSZE * 2 - hstates);
    float* h1f = (float*)alloc((size_t)HSZE * 4);
    unsigned* bar = (unsigned*)alloc(1024);

    hipMemsetAsync(hstates, 0, hstate_bytes, stream);
    hipMemsetAsync(bar, 0, 1024, stream);

    transpose_w_kernel<<<dim3(1536 / 64, 16, 4), 256, 0, stream>>>(
        W0[0], W0[1], W0[2], W0[3], wt0, 1536);
    transpose_w_kernel<<<dim3(2048 / 64, 16, 4), 256, 0, stream>>>(
        W1[0], W1[1], W1[2], W1[3], wt1, 2048);
    cvt_x_frag_kernel<<<dim3(64, 8), 256, 0, stream>>>(x, xb);

    lstm_persist_kernel<<<NBLK, 512, 0, stream>>>(
        wt0, wt1, xb,
        B0[0], B0[1], B0[2], B0[3],
        B1[0], B1[1], B1[2], B1[3],
        h0b, h1b, h1f, bar);

    classifier_kernel<<<dim3(4, 64), 256, 0, stream>>>(h1f, Wc, bc, out);
    softmax_kernel<<<NBATCH, 256, 0, stream>>>(out, out + (size_t)NBATCH * 1000);
}

// Round 19
// 1411.736 us; speedup vs baseline: 1.0573x; 1.0573x over previous
//
#include <hip/hip_runtime.h>
#include <hip/hip_bf16.h>

// ---------------------------------------------------------------------------
// LSTM_37847251812594: 2-layer LSTM (B=256, T=64, n_x=512, n_h=1024) + FC+softmax
// Round 19: REVERT to round-17 champion (1400 us) — r18's 32x32 trade lost
// (halved LDS A-traffic but halved TLP; latency residue dominates).
//   - 256 blk x 1024 thr (16 waves, 4 waves/SIMD), layer-split blocks,
//     8 hidden/block, LDS-resident weights, frag-major h/x, shfl epilogue,
//     k-rotation, unroll-8 I$-safe loops.
//   - decoupled per-layer barriers (128 blocks each) + 4-slot h0 ring with
//     epoch flow control: L0 free-runs <=3 intervals ahead of L1.
// Lever matrix exhausted over r11-r18: deep-ILP x3 fail (I$), TLP r14 +9%,
// traffic r16/r18 neutral-fail, sync r17 +2.5%. Structural limit: 64 serial
// intervals x (L2 broadcast + barrier) ~21 us.
// ---------------------------------------------------------------------------

typedef short  bf16x8 __attribute__((ext_vector_type(8)));
typedef float  f32x4  __attribute__((ext_vector_type(4)));

#define NHID   1024
#define NBATCH 256
#define NBLK   256
#define HSZE   (NBATCH * NHID)

__device__ __forceinline__ unsigned short f2b(float f) {
    unsigned int u = __builtin_bit_cast(unsigned int, f);
    unsigned int r = (u + 0x7FFFu + ((u >> 16) & 1u)) >> 16;
    return (unsigned short)r;
}
__device__ __forceinline__ float sigmoidf_(float x) {
    return 1.0f / (1.0f + __expf(-x));
}
__device__ __forceinline__ float tanhf_(float x) {
    return 1.0f - 2.0f / (__expf(2.0f * x) + 1.0f);
}

// Transpose+convert: W[k][n] fp32 -> Wt[g][n][k] bf16, LDS-tiled 64x64.
__global__ __launch_bounds__(256)
void transpose_w_kernel(const float* __restrict__ w0, const float* __restrict__ w1,
                        const float* __restrict__ w2, const float* __restrict__ w3,
                        unsigned short* __restrict__ dst, int nv) {
    __shared__ unsigned short t[64][65];
    const int gate = blockIdx.z;
    const float* src = (gate == 0) ? w0 : (gate == 1) ? w1 : (gate == 2) ? w2 : w3;
    const int kt = blockIdx.x * 64;
    const int nt = blockIdx.y * 64;
    const int tid = threadIdx.x;
    const int rr = tid >> 6;
    const int cc = tid & 63;
    #pragma unroll
    for (int p = 0; p < 16; ++p) {
        const int row = p * 4 + rr;
        t[cc][row] = f2b(src[(size_t)(kt + row) * NHID + nt + cc]);
    }
    __syncthreads();
    #pragma unroll
    for (int p = 0; p < 16; ++p) {
        const int row = p * 4 + rr;
        dst[((size_t)gate * NHID + nt + row) * nv + kt + cc] = t[row][cc];
    }
}

// x -> bf16, FRAGMENT-MAJOR per timestep:
// xb[t][mg][c][lane][8], lane = koct*16 + row, k = c*32 + koct*8 + e.
__global__ __launch_bounds__(256)
void cvt_x_frag_kernel(const float* __restrict__ x, unsigned short* __restrict__ xb) {
    const int t  = blockIdx.x;        // 0..63
    const int mg = blockIdx.y;        // 0..15
    const int g  = threadIdx.x >> 6;  // 0..3
    const int l  = threadIdx.x & 63;
    const int row = l & 15, ko = l >> 4;
    const float* src = x + (size_t)(mg * 16 + row) * 32768 + t * 512 + ko * 8;
    unsigned short* dst = xb + ((size_t)t * 256 * 512) + ((size_t)mg * 16 * 64 + l) * 8;
    #pragma unroll
    for (int i = 0; i < 4; ++i) {
        const int c = g * 4 + i;
        const float4 v0 = *(const float4*)(src + (size_t)c * 32);
        const float4 v1 = *(const float4*)(src + (size_t)c * 32 + 4);
        ushort4 o0, o1;
        o0.x = f2b(v0.x); o0.y = f2b(v0.y); o0.z = f2b(v0.z); o0.w = f2b(v0.w);
        o1.x = f2b(v1.x); o1.y = f2b(v1.y); o1.z = f2b(v1.z); o1.w = f2b(v1.w);
        *(ushort4*)(dst + (size_t)c * 512)     = o0;
        *(ushort4*)(dst + (size_t)c * 512 + 4) = o1;
    }
}

// Per-layer group barrier (128 blocks: 4 groups x 32), monotone counters,
// relaxed agent atomics, one release fence before arrive + one acquire after.
// Cross-layer epoch gating:
//   L1 (after its barrier for iter gen): wait gctr_L0 >= gen+1.
//   L0 (gen>=2): wait gctr_L1 >= gen-1 (h0 ring depth 4).
__device__ __forceinline__ void layer_sync(unsigned* bar, unsigned gen,
                                           int layer, int lb) {
    __syncthreads();
    if (threadIdx.x == 0) {
        __builtin_amdgcn_fence(__ATOMIC_RELEASE, "agent");
        unsigned* base = bar + layer * 96;
        unsigned* grp  = base + (lb & 3) * 16;
        unsigned* stg  = base + 64;
        unsigned* gctr = base + 80;
        unsigned* octr = bar + (layer ? 80 : 176);
        if (__hip_atomic_fetch_add(grp, 1u, __ATOMIC_RELAXED, __HIP_MEMORY_SCOPE_AGENT)
                == gen * 32u + 31u) {
            if (__hip_atomic_fetch_add(stg, 1u, __ATOMIC_RELAXED, __HIP_MEMORY_SCOPE_AGENT)
                    == gen * 4u + 3u)
                __hip_atomic_store(gctr, gen + 1u, __ATOMIC_RELAXED, __HIP_MEMORY_SCOPE_AGENT);
        }
        while (__hip_atomic_load(gctr, __ATOMIC_RELAXED, __HIP_MEMORY_SCOPE_AGENT) <= gen)
            __builtin_amdgcn_s_sleep(2);
        if (layer == 1) {
            while (__hip_atomic_load(octr, __ATOMIC_RELAXED, __HIP_MEMORY_SCOPE_AGENT) <= gen)
                __builtin_amdgcn_s_sleep(2);
        } else if (gen >= 2) {
            while (__hip_atomic_load(octr, __ATOMIC_RELAXED, __HIP_MEMORY_SCOPE_AGENT) < gen - 1u)
                __builtin_amdgcn_s_sleep(2);
        }
        __builtin_amdgcn_fence(__ATOMIC_ACQUIRE, "agent");
    }
    __syncthreads();
}

// Persistent kernel, layer-split, 1024 threads = 16 waves (r14 structure).
__global__ __launch_bounds__(1024, 4)
void lstm_persist_kernel(const unsigned short* __restrict__ wt0,   // [4][1024][1536]
                         const unsigned short* __restrict__ wt1,   // [4][1024][2048]
                         const unsigned short* __restrict__ xb,    // frag-major [64][...]
                         const float* __restrict__ bf0, const float* __restrict__ bi0,
                         const float* __restrict__ bc0, const float* __restrict__ bo0,
                         const float* __restrict__ bf1, const float* __restrict__ bi1,
                         const float* __restrict__ bc1, const float* __restrict__ bo1,
                         unsigned short* __restrict__ h0b,   // [4] frag-major ring
                         unsigned short* __restrict__ h1b,   // [2] frag-major
                         float* __restrict__ h1f,            // [256][1024] fp32 plain
                         unsigned* __restrict__ bar) {
    __shared__ __align__(16) unsigned short lw[65536];   // up to 128 KB

    const int tid  = threadIdx.x;
    const int lane = tid & 63;
    const int w    = tid >> 6;     // wave 0..15 -> m-group w (rows 16w..16w+15)
    const int c15  = lane & 15;
    const int kg   = lane >> 4;    // 0..3
    const int b    = blockIdx.x;
    const int layer = (b >> 3) & 1;
    const int lb    = ((b >> 4) << 3) | (b & 7);   // 0..127 within layer

    const unsigned short* wt = layer ? wt1 : wt0;
    const int NV  = layer ? 2048 : 1536;
    const int NCW = NV >> 5;            // 48 or 64 chunks

    // ---- stage this block's 32 gate-rows into LDS, fragment order ----
    #pragma unroll
    for (int i = 0; i < 4; ++i) {
        const int c = w + i * 16;
        if (c < NCW) {
            #pragma unroll
            for (int rt = 0; rt < 2; ++rt) {
                const int R   = rt * 16 + c15;
                const int g   = R >> 3;
                const int hid = 8 * lb + (R & 7);
                const int k   = c * 32 + kg * 8;
                *(bf16x8*)(lw + ((size_t)(c * 2 + rt) * 64 + lane) * 8) =
                    *(const bf16x8*)(wt + ((size_t)g * NHID + hid) * NV + k);
            }
        }
    }

    // biases: biasv[rt][j] for row R = rt*16 + kg*4 + j
    f32x4 biasv[2];
    {
        const float* bp[4];
        if (layer) { bp[0] = bf1; bp[1] = bi1; bp[2] = bc1; bp[3] = bo1; }
        else       { bp[0] = bf0; bp[1] = bi0; bp[2] = bc0; bp[3] = bo0; }
        #pragma unroll
        for (int rt = 0; rt < 2; ++rt)
            #pragma unroll
            for (int j = 0; j < 4; ++j) {
                const int R = rt * 16 + kg * 4 + j;
                biasv[rt][j] = bp[R >> 3][8 * lb + (R & 7)];
            }
    }
    __syncthreads();

    float cs[2] = {0.f, 0.f};   // 2 cells per thread (m = 16w+c15, hid hp..hp+1)
    unsigned gen = 0;

    const int rot_h  = (b >> 3) & 31;
    const int rot_xL = layer ? rot_h : ((b >> 4) & 15);

    // epilogue ownership: lane (kg,c15) handles hidden pair hp = 4*(kg&1)+2*(kg>>1)
    const int hb4  = 4 * (kg & 1);
    const int jsel = (kg >> 1) ? 2 : 0;
    const int hp   = hb4 + jsel;                 // 0,4,2,6 (even)
    const int mrow = 16 * w + c15;
    const int chw  = lb >> 2;                    // h-chunk of hidden 8lb..8lb+7
    const int kow  = lb & 3;                     // k-oct
    const size_t hoff = (((size_t)w * 32 + chw) * 64 + kow * 16 + c15) * 8 + hp;

    auto step = [&](const int NX, const int rot_x,
                    const unsigned short* bh, const unsigned short* bx,
                    unsigned short* hout, float* hfout) {
        f32x4 acc0 = biasv[0], acc1 = biasv[1];   // rt0, rt1 for m-group w
        const unsigned short* ph = bh + ((size_t)w * 32 * 64 + lane) * 8;
        const unsigned short* px = bx + ((size_t)w * NX * 64 + lane) * 8;

        #pragma unroll 8
        for (int i = 0; i < 32; ++i) {
            const int cc = (i + rot_h) & 31;
            const bf16x8 vb  = *(const bf16x8*)(ph + (size_t)cc * 512);
            const bf16x8 va0 = *(const bf16x8*)(lw + ((size_t)(cc * 2)     * 64 + lane) * 8);
            const bf16x8 va1 = *(const bf16x8*)(lw + ((size_t)(cc * 2 + 1) * 64 + lane) * 8);
            acc0 = __builtin_amdgcn_mfma_f32_16x16x32_bf16(va0, vb, acc0, 0, 0, 0);
            acc1 = __builtin_amdgcn_mfma_f32_16x16x32_bf16(va1, vb, acc1, 0, 0, 0);
        }
        #pragma unroll 8
        for (int i = 0; i < NX; ++i) {
            const int cc = (i + rot_x) & (NX - 1);
            const bf16x8 vb  = *(const bf16x8*)(px + (size_t)cc * 512);
            const bf16x8 va0 = *(const bf16x8*)(lw + ((size_t)((32 + cc) * 2)     * 64 + lane) * 8);
            const bf16x8 va1 = *(const bf16x8*)(lw + ((size_t)((32 + cc) * 2 + 1) * 64 + lane) * 8);
            acc0 = __builtin_amdgcn_mfma_f32_16x16x32_bf16(va0, vb, acc0, 0, 0, 0);
            acc1 = __builtin_amdgcn_mfma_f32_16x16x32_bf16(va1, vb, acc1, 0, 0, 0);
        }

        // gate exchange: lane kg holds rows 4kg..4kg+3 of rt0 (F:kg<2 / I:kg>=2)
        // and rt1 (C / O). Partner kg^2 supplies the complementary pair.
        f32x4 racc0, racc1;
        #pragma unroll
        for (int j = 0; j < 4; ++j) {
            racc0[j] = __shfl_xor(acc0[j], 32);
            racc1[j] = __shfl_xor(acc1[j], 32);
        }

        float hv[2];
        #pragma unroll
        for (int jj = 0; jj < 2; ++jj) {
            const int j = jsel + jj;
            float fsv, isv, csv, osv;
            if (kg < 2) { fsv = acc0[j];  isv = racc0[j]; csv = acc1[j];  osv = racc1[j]; }
            else        { fsv = racc0[j]; isv = acc0[j];  csv = racc1[j]; osv = acc1[j];  }
            const float fv = sigmoidf_(fsv);
            const float iv = sigmoidf_(isv);
            const float cv = tanhf_(csv);
            const float ov = sigmoidf_(osv);
            const float ccv = fv * cs[jj] + iv * cv;
            const float hh  = ov * tanhf_(ccv);
            cs[jj] = ccv;
            hv[jj] = hh;
        }
        const unsigned hbp = (unsigned)f2b(hv[0]) | ((unsigned)f2b(hv[1]) << 16);
        *reinterpret_cast<unsigned*>(hout + hoff) = hbp;
        if (hfout) {
            float2 hf; hf.x = hv[0]; hf.y = hv[1];
            *reinterpret_cast<float2*>(hfout + (size_t)mrow * NHID + 8 * lb + hp) = hf;
        }
    };

    // pipeline: iter t: L0-blocks do L0[t] (h0 ring slot t&3),
    //                   L1-blocks do L1[t-1]; per-layer barriers only.
    for (int t = 0; t <= 64; ++t) {
        if (layer == 0) {
            if (t < 64) {
                step(16, rot_xL,
                     h0b + (size_t)((t + 3) & 3) * HSZE,   // h0[t-1]
                     xb + (size_t)t * 256 * 512,
                     h0b + (size_t)(t & 3) * HSZE, nullptr);
            }
        } else {
            if (t >= 1) {
                const int u = t - 1;
                step(32, rot_xL,
                     h1b + (size_t)((u + 1) & 1) * HSZE,
                     h0b + (size_t)(u & 3) * HSZE,
                     h1b + (size_t)(u & 1) * HSZE,
                     (u == 63) ? h1f : nullptr);
            }
        }
        if (t < 64) {
            layer_sync(bar, gen, layer, lb);
            ++gen;
        }
    }
}

// logits = h1 @ W + b : grid (4 n-blocks, 64 m-blocks), 4 m-rows staged in LDS.
__global__ __launch_bounds__(256)
void classifier_kernel(const float* __restrict__ h, const float* __restrict__ W,
                       const float* __restrict__ b, float* __restrict__ logits) {
    __shared__ float hs[4 * 1024];
    const int tid = threadIdx.x;
    const int m0 = blockIdx.y * 4;
    const int n  = blockIdx.x * 256 + tid;
    #pragma unroll
    for (int i = 0; i < 16; ++i)
        hs[i * 256 + tid] = h[(size_t)m0 * NHID + i * 256 + tid];
    __syncthreads();
    if (n < 1000) {
        float a0 = 0.f, a1 = 0.f, a2 = 0.f, a3 = 0.f;
        #pragma unroll 8
        for (int k = 0; k < NHID; ++k) {
            const float wv = W[(size_t)k * 1000 + n];
            a0 = fmaf(hs[k], wv, a0);
            a1 = fmaf(hs[1024 + k], wv, a1);
            a2 = fmaf(hs[2048 + k], wv, a2);
            a3 = fmaf(hs[3072 + k], wv, a3);
        }
        const float bv = b[n];
        logits[(size_t)(m0 + 0) * 1000 + n] = a0 + bv;
        logits[(size_t)(m0 + 1) * 1000 + n] = a1 + bv;
        logits[(size_t)(m0 + 2) * 1000 + n] = a2 + bv;
        logits[(size_t)(m0 + 3) * 1000 + n] = a3 + bv;
    }
}

__global__ void softmax_kernel(const float* __restrict__ logits, float* __restrict__ pred) {
    __shared__ float red[256];
    const int m = blockIdx.x;
    const int t = threadIdx.x;
    const float* lr = logits + (size_t)m * 1000;
    float mx = -3.4e38f;
    for (int i = t; i < 1000; i += 256) mx = fmaxf(mx, lr[i]);
    red[t] = mx; __syncthreads();
    for (int off = 128; off > 0; off >>= 1) {
        if (t < off) red[t] = fmaxf(red[t], red[t + off]);
        __syncthreads();
    }
    mx = red[0];
    __syncthreads();
    float sm = 0.0f;
    for (int i = t; i < 1000; i += 256) sm += __expf(lr[i] - mx);
    red[t] = sm; __syncthreads();
    for (int off = 128; off > 0; off >>= 1) {
        if (t < off) red[t] += red[t + off];
        __syncthreads();
    }
    const float inv = 1.0f / red[0];
    for (int i = t; i < 1000; i += 256)
        pred[(size_t)m * 1000 + i] = __expf(lr[i] - mx) * inv;
}

extern "C" void kernel_launch(void* const* d_in, const int* in_sizes, int n_in,
                              void* d_out, int out_size, void* d_ws, size_t ws_size,
                              hipStream_t stream) {
    (void)in_sizes; (void)n_in; (void)out_size; (void)ws_size;
    const float* x = (const float*)d_in[0];
    const float* W0[4] = {(const float*)d_in[1], (const float*)d_in[2], (const float*)d_in[3], (const float*)d_in[4]};
    const float* B0[4] = {(const float*)d_in[5], (const float*)d_in[6], (const float*)d_in[7], (const float*)d_in[8]};
    const float* W1[4] = {(const float*)d_in[9], (const float*)d_in[10], (const float*)d_in[11], (const float*)d_in[12]};
    const float* B1[4] = {(const float*)d_in[13], (const float*)d_in[14], (const float*)d_in[15], (const float*)d_in[16]};
    const float* Wc = (const float*)d_in[17];
    const float* bc = (const float*)d_in[18];
    float* out = (float*)d_out;

    char* ws = (char*)d_ws;
    size_t off = 0;
    auto alloc = [&](size_t bytes) -> char* {
        char* p = ws + off;
        off += (bytes + 255) & ~(size_t)255;
        return p;
    };
    unsigned short* wt0 = (unsigned short*)alloc((size_t)4 * NHID * 1536 * 2);
    unsigned short* wt1 = (unsigned short*)alloc((size_t)4 * NHID * 2048 * 2);
    unsigned short* xb  = (unsigned short*)alloc((size_t)NBATCH * 64 * 512 * 2);
    char* hstates = ws + off;
    unsigned short* h0b = (unsigned short*)alloc((size_t)4 * HSZE * 2);   // 4-slot ring
    unsigned short* h1b = (unsigned short*)alloc((size_t)2 * HSZE * 2);
    size_t hstate_bytes = (size_t)((char*)h1b + (size_t)2 * HSZE * 2 - hstates);
    float* h1f = (float*)alloc((size_t)HSZE * 4);
    unsigned* bar = (unsigned*)alloc(1024);

    hipMemsetAsync(hstates, 0, hstate_bytes, stream);
    hipMemsetAsync(bar, 0, 1024, stream);

    transpose_w_kernel<<<dim3(1536 / 64, 16, 4), 256, 0, stream>>>(
        W0[0], W0[1], W0[2], W0[3], wt0, 1536);
    transpose_w_kernel<<<dim3(2048 / 64, 16, 4), 256, 0, stream>>>(
        W1[0], W1[1], W1[2], W1[3], wt1, 2048);
    cvt_x_frag_kernel<<<dim3(64, 16), 256, 0, stream>>>(x, xb);

    lstm_persist_kernel<<<NBLK, 1024, 0, stream>>>(
        wt0, wt1, xb,
        B0[0], B0[1], B0[2], B0[3],
        B1[0], B1[1], B1[2], B1[3],
        h0b, h1b, h1f, bar);

    classifier_kernel<<<dim3(4, 64), 256, 0, stream>>>(h1f, Wc, bc, out);
    softmax_kernel<<<NBATCH, 256, 0, stream>>>(out, out + (size_t)NBATCH * 1000);
}